// Round 16
// baseline (805.545 us; speedup 1.0000x reference)
//
#include <hip/hip_runtime.h>

typedef unsigned short u16;
typedef u16   u16x4 __attribute__((ext_vector_type(4)));
typedef u16   u16x8 __attribute__((ext_vector_type(8)));
typedef short s16x8 __attribute__((ext_vector_type(8)));
typedef float f32x4 __attribute__((ext_vector_type(4)));

// Model dims
#define NV 32000
#define NT 256
#define NC 384
#define NH 6
#define ND 64
#define NL 6
#define NB 16
#define NFF 1536
#define NM (NB*NT)          // 4096 rows
#define QKVSZ (NB*NH*NT*ND) // 1572864 elems per tensor
#define NSLAB (NV/32)       // 1000 loss slabs per row (head BN=64 -> 2 slabs of 32 per block)

__device__ __forceinline__ u16 f2bf(float f){
    unsigned x = __builtin_bit_cast(unsigned, f);
    x += 0x7fffu + ((x>>16)&1u);
    return (u16)(x>>16);
}

__device__ __forceinline__ void gload_lds16(const u16* g, u16* l){
    __builtin_amdgcn_global_load_lds((const __attribute__((address_space(1))) unsigned int*)g,
                                     (__attribute__((address_space(3))) unsigned int*)l, 16, 0, 0);
}

// ---------------- embedding: raw x (fp32 + bf16) + row stats ----------------
__global__ __launch_bounds__(256) void embed_stats(const int* __restrict__ ids,
        const float* __restrict__ tok, const float* __restrict__ pos,
        float* __restrict__ x, u16* __restrict__ xb, float* __restrict__ statp){
    int row  = blockIdx.x*4 + (threadIdx.x>>6);
    int lane = threadIdx.x & 63;
    int t = row & (NT-1);
    const float* tr = tok + (size_t)ids[row]*NC;
    const float* pr = pos + (size_t)t*NC;
    float* xr = x + (size_t)row*NC;
    u16* br = xb + (size_t)row*NC;
    float sum = 0.f, sq = 0.f;
    #pragma unroll
    for (int i=0;i<6;++i){
        int c = lane+64*i;
        float v = tr[c] + pr[c];
        xr[c] = v; br[c] = f2bf(v);
        sum += v; sq += v*v;
    }
    #pragma unroll
    for (int off=1; off<64; off<<=1){ sum += __shfl_xor(sum,off); sq += __shfl_xor(sq,off); }
    if (lane == 0){
        float* pp = statp + (size_t)row*6;
        pp[0]=sum; pp[1]=sq; pp[2]=0.f; pp[3]=0.f; pp[4]=0.f; pp[5]=0.f;
    }
}

// ---------------- merged transpose-convert (folds LN scale + qscale into weights) ----------------
struct TDesc {
    const float* in; u16* out;
    int Cc; int nx; int perZ; int obDiv; int oStride; int start;
    long inBatch; long oS1; long oS2; float scale;
    const float* svec; long svecS;
};
struct TPack { TDesc d[7]; };

__global__ __launch_bounds__(256) void tconv_all(TPack p){
    __shared__ float tile[32][33];
    int bid = blockIdx.x;
    int e = 0;
    #pragma unroll
    for (int i=1;i<7;++i) e += (bid >= p.d[i].start) ? 1 : 0;
    TDesc D = p.d[e];
    int local = bid - D.start;
    int bz  = local / D.perZ; int rem = local - bz*D.perZ;
    int cy  = rem / D.nx;     int cx  = rem - cy*D.nx;
    int r0 = cy*32, c0 = cx*32;
    const float* ib = D.in + (size_t)bz*D.inBatch;
    u16* ob = D.out + (size_t)(bz/D.obDiv)*D.oS1 + (size_t)(bz%D.obDiv)*D.oS2;
    const float* sv = D.svec ? D.svec + (size_t)(bz/D.obDiv)*D.svecS : nullptr;
    int tx = threadIdx.x & 31, ty = threadIdx.x >> 5;   // 32 x 8
    #pragma unroll
    for (int i=0;i<4;++i) tile[ty+8*i][tx] = ib[(size_t)(r0+ty+8*i)*D.Cc + (c0+tx)];
    __syncthreads();
    float f = D.scale * (sv ? sv[r0+tx] : 1.f);
    #pragma unroll
    for (int i=0;i<4;++i) ob[(size_t)(c0+ty+8*i)*D.oStride + (r0+tx)] = f2bf(tile[tx][ty+8*i]*f);
}

// ---------------- u/v precompute: u[n]=sum_k s[k]W[k,n], v[n]=sum_k b[k]W[k,n] ----------------
struct UVArgs {
    const float *Wq,*Wk,*Wv,*W1,*Wh;
    const float *ln1s,*ln1b,*ln2s,*ln2b,*lnfs,*lnfb;
    float *uvq, *uvf, *uvh; float qscale;
};
__global__ __launch_bounds__(256) void uv_kernel(UVArgs a){
    int gid = blockIdx.x*256 + threadIdx.x;
    const float *W, *s, *b; int kst; float sc = 1.f; float *ou, *ov;
    if (gid < 6*1152){
        int l = gid/1152, n = gid - l*1152;
        int which = n/384, hd = n - which*384, h = hd>>6, d = hd&63;
        const float* Ws = which==0 ? a.Wq : (which==1 ? a.Wk : a.Wv);
        W = Ws + ((size_t)(l*NH+h))*NC*ND + d;
        kst = ND;
        s = a.ln1s + l*NC; b = a.ln1b + l*NC;
        if (which==0) sc = a.qscale;
        ou = a.uvq + (size_t)l*2*1152 + n; ov = ou + 1152;
    } else if (gid < 6*1152 + 6*1536){
        int g = gid - 6*1152; int l = g/1536, f = g - l*1536;
        W = a.W1 + (size_t)l*NC*NFF + f; kst = NFF;
        s = a.ln2s + l*NC; b = a.ln2b + l*NC;
        ou = a.uvf + (size_t)l*2*1536 + f; ov = ou + 1536;
    } else {
        int n = gid - (6*1152 + 6*1536);
        W = a.Wh + n; kst = NV;
        s = a.lnfs; b = a.lnfb;
        ou = a.uvh + n; ov = ou + NV;
    }
    float u = 0.f, v = 0.f;
    for (int k=0;k<NC;++k){ float w = W[(size_t)k*kst]; u += s[k]*w; v += b[k]*w; }
    *ou = u*sc; *ov = v*sc;
}

// ---------------- generic bf16 MFMA GEMM, C = A[M,K] * Bt[N,K]^T ----------------
// r6/r11 structure: BK=64 single-buffer, (256,4). LNF=1: weights are s-folded; epilogue
// applies C = r_m*(G - mu_m*u[n]) + v[n] using stats from statp.
template<int EPI, int BM, int BN, int LNF>
__global__ __launch_bounds__(256,4) void gemm_bt(
        const u16* __restrict__ A, const u16* __restrict__ Bt,
        const float* __restrict__ bias, float* __restrict__ resid,
        u16* __restrict__ outb,
        const float* __restrict__ statp, const float* __restrict__ uvec,
        const float* __restrict__ vvec, float* __restrict__ stout,
        int M, int N, int K){
    constexpr int WM = BM/2, WN = BN/2, MI = WM/16, NI = WN/16;
    __shared__ u16 As[2*BM*32];
    __shared__ u16 Bs[2*BN*32];
    __shared__ float stM[LNF?BM:1], stR[LNF?BM:1];
    __shared__ float sS[2][16][2], sQ[2][16][2];
    int tid = threadIdx.x;
    int lane = tid & 63, wid = tid >> 6;
    int wm = wid >> 1, wn = wid & 1;
    int l15 = lane & 15, lg = lane >> 4;
    int bx = blockIdx.x, by = blockIdx.y;
    int m0 = by * BM, n0 = bx * BN;

    if constexpr (LNF){
        if (tid < BM){
            const float* pp = statp + (size_t)(m0+tid)*6;
            float s = pp[0]+pp[2]+pp[4];
            float q = pp[1]+pp[3]+pp[5];
            float mu = s*(1.f/NC);
            stM[tid] = mu;
            stR[tid] = rsqrtf(q*(1.f/NC) - mu*mu + 1e-5f);
        }
        __syncthreads();
    }

    f32x4 acc[MI][NI];
    #pragma unroll
    for (int a=0;a<MI;++a)
        #pragma unroll
        for (int b=0;b<NI;++b) acc[a][b] = f32x4{0.f,0.f,0.f,0.f};

    int nk = K >> 6;
    for (int kk = 0; kk < nk; ++kk){
        int k0 = kk << 6;
        #pragma unroll
        for (int h=0;h<2;++h){
            if constexpr (BM >= 64){
                #pragma unroll
                for (int i=0;i<BM/64;++i){
                    int o   = i*4096 + tid*16;
                    int row = o >> 6;
                    int kb  = (o & 63) >> 1;
                    gload_lds16(A + (size_t)(m0+row)*K + (k0+h*32+kb), &As[h*BM*32 + (o>>1)]);
                }
            } else {
                if (tid < BM*4){
                    int o = tid*16;
                    int row = o >> 6;
                    int kb  = (o & 63) >> 1;
                    gload_lds16(A + (size_t)(m0+row)*K + (k0+h*32+kb), &As[h*BM*32 + (o>>1)]);
                }
            }
            #pragma unroll
            for (int i=0;i<BN/64;++i){
                int o   = i*4096 + tid*16;
                int row = o >> 6;
                int kb  = (o & 63) >> 1;
                gload_lds16(Bt + (size_t)(n0+row)*K + (k0+h*32+kb), &Bs[h*BN*32 + (o>>1)]);
            }
        }
        asm volatile("s_waitcnt vmcnt(0)" ::: "memory");
        __syncthreads();
        #pragma unroll
        for (int ks=0;ks<2;++ks){
            s16x8 af[MI];
            #pragma unroll
            for (int mi=0;mi<MI;++mi) af[mi] = *(const s16x8*)&As[ks*BM*32 + (wm*WM+mi*16+l15)*32 + lg*8];
            #pragma unroll
            for (int ni=0;ni<NI;++ni){
                s16x8 bfr = *(const s16x8*)&Bs[ks*BN*32 + (wn*WN+ni*16+l15)*32 + lg*8];
                #pragma unroll
                for (int mi=0;mi<MI;++mi)
                    acc[mi][ni] = __builtin_amdgcn_mfma_f32_16x16x32_bf16(af[mi], bfr, acc[mi][ni], 0,0,0);
            }
        }
        __syncthreads();
    }

    if (EPI == 1){
        float rs[4]={0.f,0.f,0.f,0.f}, rq[4]={0.f,0.f,0.f,0.f};
        #pragma unroll
        for (int ni=0;ni<NI;++ni)
            #pragma unroll
            for (int r=0;r<4;++r){
                int mg = m0 + wm*WM + lg*4 + r;
                int ng = n0 + wn*WN + ni*16 + l15;
                float* pp = resid + (size_t)mg*NC + ng;
                float val = acc[0][ni][r] + bias[ng] + *pp;
                *pp = val;
                outb[(size_t)mg*NC + ng] = f2bf(val);
                rs[r] += val; rq[r] += val*val;
            }
        #pragma unroll
        for (int r=0;r<4;++r){
            rs[r]+=__shfl_xor(rs[r],1); rq[r]+=__shfl_xor(rq[r],1);
            rs[r]+=__shfl_xor(rs[r],2); rq[r]+=__shfl_xor(rq[r],2);
            rs[r]+=__shfl_xor(rs[r],4); rq[r]+=__shfl_xor(rq[r],4);
            rs[r]+=__shfl_xor(rs[r],8); rq[r]+=__shfl_xor(rq[r],8);
            if (l15==0){ sS[wm][lg*4+r][wn]=rs[r]; sQ[wm][lg*4+r][wn]=rq[r]; }
        }
        __syncthreads();
        if (tid < 32){
            int wmi = tid>>4, rr = tid&15;
            float s = sS[wmi][rr][0] + sS[wmi][rr][1];
            float q = sQ[wmi][rr][0] + sQ[wmi][rr][1];
            float* pp = stout + (size_t)(m0+tid)*6 + bx*2;
            pp[0]=s; pp[1]=q;
        }
        return;
    }

    #pragma unroll
    for (int mi=0;mi<MI;++mi){
        #pragma unroll
        for (int ni=0;ni<NI;++ni){
            int ng = n0 + wn*WN + ni*16 + l15;
            if (EPI == 0){
                int which = ng / NC; int hd = ng - which*NC;
                int hh = hd >> 6, d = hd & 63;
                int mgb = m0 + wm*WM + mi*16 + lg*4;
                int bb = mgb >> 8, tt = mgb & (NT-1);
                float uu = uvec[ng], vv0 = vvec[ng];
                if (which == 2){
                    u16x4 v;
                    #pragma unroll
                    for (int r=0;r<4;++r){
                        int lr = wm*WM + mi*16 + lg*4 + r;
                        v[r] = f2bf(stR[lr]*(acc[mi][ni][r] - stM[lr]*uu) + vv0);
                    }
                    *(u16x4*)(outb + (size_t)2*QKVSZ + ((size_t)(bb*NH+hh)*ND + d)*NT + tt) = v;
                } else {
                    #pragma unroll
                    for (int r=0;r<4;++r){
                        int lr = wm*WM + mi*16 + lg*4 + r;
                        float val = stR[lr]*(acc[mi][ni][r] - stM[lr]*uu) + vv0;
                        outb[(size_t)which*QKVSZ + ((size_t)(bb*NH+hh)*NT + tt+r)*ND + d] = f2bf(val);
                    }
                }
            } else {   // EPI == 2 (FF1 relu)
                float uu = uvec[ng], vv0 = vvec[ng] + bias[ng];
                #pragma unroll
                for (int r=0;r<4;++r){
                    int lr = wm*WM + mi*16 + lg*4 + r;
                    int mg = m0 + lr;
                    float val = stR[lr]*(acc[mi][ni][r] - stM[lr]*uu) + vv0;
                    outb[(size_t)mg*N + ng] = f2bf(fmaxf(val, 0.f));
                }
            }
        }
    }
}

// ---------------- head GEMM: LN-folded logits + loss partials ----------------
// High-occupancy variant: BM=128 x BN=64, acc=32 VGPRs, single-buffer BK=32 (12KB LDS),
// (256,8) -> 8 blocks/CU (32 waves). Latency hidden by TLP (r6 lesson at max setting).
__global__ __launch_bounds__(256,8) void gemm_head(
        const u16* __restrict__ A, const u16* __restrict__ Bt,
        const float* __restrict__ bias,
        const float* __restrict__ statp, const float* __restrict__ uvec,
        const float* __restrict__ vvec,
        float* __restrict__ outf, float* __restrict__ lpart,
        int M, int N, int K){
    constexpr int BM=128, BN=64, WM=64, WN=32, MI=4, NI=2;
    __shared__ u16 As[BM*32];
    __shared__ u16 Bs[BN*32];
    __shared__ float stM[BM], stR[BM];
    int tid = threadIdx.x;
    int lane = tid & 63, wid = tid >> 6;
    int wm = wid >> 1, wn = wid & 1;
    int l15 = lane & 15, lg = lane >> 4;
    int nwg = gridDim.x*gridDim.y;            // 16000, %8==0
    int orig = blockIdx.y*gridDim.x + blockIdx.x;
    int swz = (orig&7)*(nwg>>3) + (orig>>3);
    int by = swz & 31;                        // gridDim.y == 32
    int bx = swz >> 5;
    int m0 = by * BM, n0 = bx * BN;

    if (tid < BM){
        const float* pp = statp + (size_t)(m0+tid)*6;
        float s = pp[0]+pp[2]+pp[4];
        float q = pp[1]+pp[3]+pp[5];
        float mu = s*(1.f/NC);
        stM[tid] = mu;
        stR[tid] = rsqrtf(q*(1.f/NC) - mu*mu + 1e-5f);
    }
    __syncthreads();

    f32x4 acc[MI][NI];
    #pragma unroll
    for (int a=0;a<MI;++a)
        #pragma unroll
        for (int b=0;b<NI;++b) acc[a][b] = f32x4{0.f,0.f,0.f,0.f};

    int nk = K >> 5;                           // 12
    for (int kk = 0; kk < nk; ++kk){
        int k0 = kk << 5;
        #pragma unroll
        for (int i=0;i<2;++i){
            int o   = i*4096 + tid*16;
            int row = o >> 6;
            int kb  = (o & 63) >> 1;
            gload_lds16(A + (size_t)(m0+row)*K + (k0+kb), &As[o>>1]);
        }
        {
            int o   = tid*16;
            int row = o >> 6;
            int kb  = (o & 63) >> 1;
            gload_lds16(Bt + (size_t)(n0+row)*K + (k0+kb), &Bs[o>>1]);
        }
        asm volatile("s_waitcnt vmcnt(0)" ::: "memory");
        __syncthreads();
        s16x8 af[MI];
        #pragma unroll
        for (int mi=0;mi<MI;++mi) af[mi] = *(const s16x8*)&As[(wm*WM+mi*16+l15)*32 + lg*8];
        #pragma unroll
        for (int ni=0;ni<NI;++ni){
            s16x8 bfr = *(const s16x8*)&Bs[(wn*WN+ni*16+l15)*32 + lg*8];
            #pragma unroll
            for (int mi=0;mi<MI;++mi)
                acc[mi][ni] = __builtin_amdgcn_mfma_f32_16x16x32_bf16(af[mi], bfr, acc[mi][ni], 0,0,0);
        }
        __syncthreads();
    }

    float es[MI][4];
    #pragma unroll
    for (int mi=0;mi<MI;++mi)
        #pragma unroll
        for (int r=0;r<4;++r) es[mi][r] = 0.f;
    #pragma unroll
    for (int mi=0;mi<MI;++mi)
        #pragma unroll
        for (int ni=0;ni<NI;++ni){
            int ng = n0 + wn*WN + ni*16 + l15;
            float uu = uvec[ng], vv0 = vvec[ng] + bias[ng];
            #pragma unroll
            for (int r=0;r<4;++r){
                int lr = wm*WM + mi*16 + lg*4 + r;
                int mg = m0 + lr;
                float val = stR[lr]*(acc[mi][ni][r] - stM[lr]*uu) + vv0;
                outf[(size_t)mg*N + ng] = val;
                es[mi][r] += __expf(val);
            }
        }
    #pragma unroll
    for (int mi=0;mi<MI;++mi)
        #pragma unroll
        for (int r=0;r<4;++r){
            float s = es[mi][r];
            s += __shfl_xor(s,1); s += __shfl_xor(s,2);
            s += __shfl_xor(s,4); s += __shfl_xor(s,8);
            if (l15 == 0){
                int mg = m0 + wm*WM + mi*16 + lg*4 + r;
                lpart[(size_t)mg*NSLAB + bx*2 + wn] = s;
            }
        }
}

// ---------------- fused causal attention: block per (b,h,qtile64), 4 waves x 16 rows ----------------
__global__ __launch_bounds__(256,2) void attn_kernel(const u16* __restrict__ qkv, u16* __restrict__ o){
    int blk = blockIdx.x;
    int qt = blk & 3, bh = blk >> 2;
    int b = bh / NH, h = bh - b*NH;
    int tid = threadIdx.x, lane = tid & 63, w = tid >> 6;
    int l15 = lane & 15, lg = lane >> 4;
    __shared__ u16 Ks[256*72];
    __shared__ u16 Vt[64*264];
    __shared__ u16 Ps[4][16*72];
    const u16* qb = qkv + (size_t)bh*NT*ND;
    const u16* kb = qkv + QKVSZ + (size_t)bh*NT*ND;
    const u16* vb = qkv + (size_t)2*QKVSZ + (size_t)bh*ND*NT;   // transposed [d][t]
    int nit = (qt+1)*2;
    for (int it=0; it<nit; ++it){
        int e0 = (it*256 + tid)*8;
        int row = e0 >> 6, col = e0 & 63;
        *(u16x8*)&Ks[row*72+col] = *(const u16x8*)(kb + e0);
    }
    for (int kt2=0; kt2<=qt; ++kt2){
        #pragma unroll
        for (int it=0; it<2; ++it){
            int e0 = (it*256 + tid)*8;
            int d = e0 >> 6, t = e0 & 63;
            *(u16x8*)&Vt[d*264 + kt2*64 + t] = *(const u16x8*)(vb + (size_t)d*NT + kt2*64 + t);
        }
    }
    const u16* qrow = qb + (size_t)(qt*64 + w*16 + l15)*ND;
    s16x8 qf[2];
    qf[0] = *(const s16x8*)(qrow + lg*8);
    qf[1] = *(const s16x8*)(qrow + 32 + lg*8);
    __syncthreads();

    f32x4 oacc[4]; float l_[4];
    #pragma unroll
    for (int c=0;c<4;++c){ oacc[c]=f32x4{0.f,0.f,0.f,0.f}; l_[c]=0.f; }
    u16* Pw = &Ps[w][0];

    for (int kt=0; kt<=qt; ++kt){
        f32x4 sacc[4];
        #pragma unroll
        for (int c=0;c<4;++c) sacc[c]=f32x4{0.f,0.f,0.f,0.f};
        #pragma unroll
        for (int ks=0;ks<2;++ks){
            s16x8 kf[4];
            #pragma unroll
            for (int ni=0;ni<4;++ni)
                kf[ni] = *(const s16x8*)&Ks[(kt*64+ni*16+l15)*72 + ks*32 + lg*8];
            #pragma unroll
            for (int ni=0;ni<4;++ni)
                sacc[ni] = __builtin_amdgcn_mfma_f32_16x16x32_bf16(qf[ks], kf[ni], sacc[ni], 0,0,0);
        }
        if (kt == qt){
            #pragma unroll
            for (int ni=0;ni<4;++ni)
                #pragma unroll
                for (int r=0;r<4;++r)
                    if (ni*16+l15 > w*16+lg*4+r) sacc[ni][r] = -1e30f;
        }
        #pragma unroll
        for (int r=0;r<4;++r){
            float rs = 0.f;
            #pragma unroll
            for (int ni=0;ni<4;++ni){
                float p = __expf(sacc[ni][r]);
                sacc[ni][r] = p;
                rs += p;
                Pw[(lg*4+r)*72 + ni*16 + l15] = f2bf(p);
            }
            rs += __shfl_xor(rs,1); rs += __shfl_xor(rs,2);
            rs += __shfl_xor(rs,4); rs += __shfl_xor(rs,8);
            l_[r] += rs;
        }
        #pragma unroll
        for (int ks=0;ks<2;++ks){
            s16x8 pf, vf[4];
            pf = *(const s16x8*)&Pw[l15*72 + ks*32 + lg*8];
            #pragma unroll
            for (int ni=0;ni<4;++ni)
                vf[ni] = *(const s16x8*)&Vt[(ni*16+l15)*264 + kt*64 + ks*32 + lg*8];
            #pragma unroll
            for (int ni=0;ni<4;++ni)
                oacc[ni] = __builtin_amdgcn_mfma_f32_16x16x32_bf16(pf, vf[ni], oacc[ni], 0,0,0);
        }
    }
    #pragma unroll
    for (int ni=0;ni<4;++ni)
        #pragma unroll
        for (int r=0;r<4;++r){
            int t = qt*64 + w*16 + lg*4 + r;
            int d = ni*16 + l15;
            o[((size_t)(b*NT + t))*NC + h*ND + d] = f2bf(oacc[ni][r] / l_[r]);
        }
}

// ---------------- loss: reduce per-row slab partials ----------------
__global__ __launch_bounds__(256) void loss_rows2(const float* __restrict__ lpart,
        const float* __restrict__ logits, const int* __restrict__ y, float* __restrict__ rowloss){
    int row  = blockIdx.x*4 + (threadIdx.x>>6);
    int lane = threadIdx.x & 63;
    const float* pr = lpart + (size_t)row*NSLAB;
    float s = 0.f;
    for (int i = lane; i < NSLAB; i += 64) s += pr[i];
    #pragma unroll
    for (int off=1; off<64; off<<=1) s += __shfl_xor(s, off);
    if (lane==0)
        rowloss[row] = logf(s) - logits[(size_t)row*NV + y[row]];
}

__global__ __launch_bounds__(256) void loss_final(const float* __restrict__ rowloss, float* __restrict__ out){
    int tid = threadIdx.x;
    float s = 0.f;
    for (int i = tid; i < NM; i += 256) s += rowloss[i];
    #pragma unroll
    for (int off=1; off<64; off<<=1) s += __shfl_xor(s, off);
    __shared__ float ss[4];
    if ((tid&63)==0) ss[tid>>6]=s;
    __syncthreads();
    if (tid==0) out[0] = (ss[0]+ss[1]+ss[2]+ss[3]) * (1.f/NM);
}

// ---------------- launch ----------------
extern "C" void kernel_launch(void* const* d_in, const int* in_sizes, int n_in,
                              void* d_out, int out_size, void* d_ws, size_t ws_size,
                              hipStream_t stream){
    const int*   x_ids = (const int*)  d_in[0];
    const int*   y_ids = (const int*)  d_in[1];
    const float* tok   = (const float*)d_in[2];
    const float* pos   = (const float*)d_in[3];
    const float* Wq    = (const float*)d_in[4];
    const float* Wk    = (const float*)d_in[5];
    const float* Wv    = (const float*)d_in[6];
    const float* Wo    = (const float*)d_in[7];
    const float* bo    = (const float*)d_in[8];
    const float* ln1s  = (const float*)d_in[9];
    const float* ln1b  = (const float*)d_in[10];
    const float* ln2s  = (const float*)d_in[11];
    const float* ln2b  = (const float*)d_in[12];
    const float* W1    = (const float*)d_in[13];
    const float* b1    = (const float*)d_in[14];
    const float* W2    = (const float*)d_in[15];
    const float* b2    = (const float*)d_in[16];
    const float* lnfs  = (const float*)d_in[17];
    const float* lnfb  = (const float*)d_in[18];
    const float* Wh    = (const float*)d_in[19];
    const float* bh    = (const float*)d_in[20];

    float* logits = (float*)d_out;
    float* lossp  = logits + (size_t)NM*NV;

    char* ws = (char*)d_ws;
    auto alloc = [&](size_t bytes)->char*{ char* p = ws; ws += (bytes + 255) & ~(size_t)255; return p; };
    float* xf    = (float*)alloc((size_t)NM*NC*4);
    u16*   xb    = (u16*)  alloc((size_t)NM*NC*2);
    float* statp = (float*)alloc((size_t)NM*6*4);
    u16*   qkvb  = (u16*)  alloc((size_t)3*QKVSZ*2);    // reused as fp32 loss partials (16.4MB <= 18.9MB)
    u16*   obf   = (u16*)  alloc((size_t)NM*NC*2);
    u16*   f1bf  = (u16*)  alloc((size_t)NM*NFF*2);
    u16*   qkvw  = (u16*)  alloc((size_t)NL*1152*NC*2);
    u16*   wot   = (u16*)  alloc((size_t)NL*NC*NC*2);
    u16*   w1t   = (u16*)  alloc((size_t)NL*NFF*NC*2);
    u16*   w2t   = (u16*)  alloc((size_t)NL*NC*NFF*2);
    u16*   wht   = (u16*)  alloc((size_t)NV*NC*2);
    float* uvq   = (float*)alloc((size_t)NL*2*1152*4);
    float* uvf   = (float*)alloc((size_t)NL*2*1536*4);
    float* uvh   = (float*)alloc((size_t)2*NV*4);
    float* part  = (float*)alloc((size_t)NM*4);
    float* lpart = (float*)qkvb;

    const float qscale = 0.051031036307982884f;   // 384^-0.5

    // ---- weight conversion (LN scale + qscale folded) ----
    TPack tp;
    tp.d[0] = {Wq, qkvw + 0*(NC*NC), ND,  2,  24, NH, NC, 0,     (long)NC*ND, (long)1152*NC, (long)ND*NC, qscale, ln1s, NC};
    tp.d[1] = {Wk, qkvw + 1*(NC*NC), ND,  2,  24, NH, NC, 864,   (long)NC*ND, (long)1152*NC, (long)ND*NC, 1.f,    ln1s, NC};
    tp.d[2] = {Wv, qkvw + 2*(NC*NC), ND,  2,  24, NH, NC, 1728,  (long)NC*ND, (long)1152*NC, (long)ND*NC, 1.f,    ln1s, NC};
    tp.d[3] = {Wo, wot,              NC, 12, 144, 1,  NC, 2592,  (long)NC*NC, (long)NC*NC,   0,           1.f,    nullptr, 0};
    tp.d[4] = {W1, w1t,             NFF, 48, 576, 1,  NC, 3456,  (long)NC*NFF,(long)NFF*NC,  0,           1.f,    ln2s, NC};
    tp.d[5] = {W2, w2t,              NC, 12, 576, 1, NFF, 6912,  (long)NFF*NC,(long)NC*NFF,  0,           1.f,    nullptr, 0};
    tp.d[6] = {Wh, wht,              NV,1000,12000,1, NC, 10368, 0,           0,             0,           1.f,    lnfs, 0};
    tconv_all<<<22368,256,0,stream>>>(tp);

    UVArgs ua = {Wq, Wk, Wv, W1, Wh, ln1s, ln1b, ln2s, ln2b, lnfs, lnfb, uvq, uvf, uvh, qscale};
    uv_kernel<<<(6*1152 + 6*1536 + NV)/256, 256, 0, stream>>>(ua);

    // ---- forward ----
    embed_stats<<<NM/4,256,0,stream>>>(x_ids, tok, pos, xf, xb, statp);
    for (int l = 0; l < NL; ++l){
        gemm_bt<0,64,128,1><<<dim3(1152/128, NM/64),256,0,stream>>>(
                xb, qkvw + (size_t)l*1152*NC, nullptr, nullptr, qkvb,
                statp, uvq + (size_t)l*2*1152, uvq + (size_t)l*2*1152 + 1152, nullptr,
                NM, 1152, NC);
        attn_kernel<<<NB*NH*4,256,0,stream>>>(qkvb, obf);
        gemm_bt<1,32,128,0><<<dim3(NC/128, NM/32),256,0,stream>>>(
                obf, wot + (size_t)l*NC*NC, bo + l*NC, xf, xb,
                nullptr, nullptr, nullptr, statp, NM, NC, NC);
        gemm_bt<2,64,128,1><<<dim3(NFF/128, NM/64),256,0,stream>>>(
                xb, w1t + (size_t)l*NFF*NC, b1 + l*NFF, nullptr, f1bf,
                statp, uvf + (size_t)l*2*1536, uvf + (size_t)l*2*1536 + 1536, nullptr,
                NM, NFF, NC);
        gemm_bt<1,32,128,0><<<dim3(NC/128, NM/32),256,0,stream>>>(
                f1bf, w2t + (size_t)l*NC*NFF, b2 + l*NC, xf, xb,
                nullptr, nullptr, nullptr, statp, NM, NC, NFF);
    }
    gemm_head<<<dim3(NV/64, NM/128),256,0,stream>>>(xb, wht, bh,
            statp, uvh, uvh + NV, logits, lpart, NM, NV, NC);
    loss_rows2<<<NM/4,256,0,stream>>>(lpart, logits, y_ids, part);
    loss_final<<<1,256,0,stream>>>(part, lossp);
}

// Round 17
// 735.172 us; speedup vs baseline: 1.0957x; 1.0957x over previous
//
#include <hip/hip_runtime.h>

typedef unsigned short u16;
typedef u16   u16x4 __attribute__((ext_vector_type(4)));
typedef u16   u16x8 __attribute__((ext_vector_type(8)));
typedef short s16x8 __attribute__((ext_vector_type(8)));
typedef float f32x4 __attribute__((ext_vector_type(4)));

// Model dims
#define NV 32000
#define NT 256
#define NC 384
#define NH 6
#define ND 64
#define NL 6
#define NB 16
#define NFF 1536
#define NM (NB*NT)          // 4096 rows
#define QKVSZ (NB*NH*NT*ND) // 1572864 elems per tensor
#define NSLAB (NV/64)       // 500 loss slabs per row (head BN=128 -> 2 slabs/block)

__device__ __forceinline__ float bf2f(u16 u){ unsigned x = ((unsigned)u)<<16; return __builtin_bit_cast(float, x); }
__device__ __forceinline__ u16 f2bf(float f){
    unsigned x = __builtin_bit_cast(unsigned, f);
    x += 0x7fffu + ((x>>16)&1u);
    return (u16)(x>>16);
}

__device__ __forceinline__ void gload_lds16(const u16* g, u16* l){
    __builtin_amdgcn_global_load_lds((const __attribute__((address_space(1))) unsigned int*)g,
                                     (__attribute__((address_space(3))) unsigned int*)l, 16, 0, 0);
}

template<int N> __device__ __forceinline__ void wait_vm(){
    static_assert(N==0 || N==4, "add literal");
    if constexpr (N==0) asm volatile("s_waitcnt vmcnt(0)" ::: "memory");
    if constexpr (N==4) asm volatile("s_waitcnt vmcnt(4)" ::: "memory");
}
__device__ __forceinline__ void bar(){
    asm volatile("" ::: "memory");
    __builtin_amdgcn_s_barrier();
    asm volatile("" ::: "memory");
}

// ---------------- embedding: bf16 x + row stats ----------------
__global__ __launch_bounds__(256) void embed_stats(const int* __restrict__ ids,
        const float* __restrict__ tok, const float* __restrict__ pos,
        u16* __restrict__ xb, float* __restrict__ statp){
    int row  = blockIdx.x*4 + (threadIdx.x>>6);
    int lane = threadIdx.x & 63;
    int t = row & (NT-1);
    const float* tr = tok + (size_t)ids[row]*NC;
    const float* pr = pos + (size_t)t*NC;
    u16* br = xb + (size_t)row*NC;
    float sum = 0.f, sq = 0.f;
    #pragma unroll
    for (int i=0;i<6;++i){
        int c = lane+64*i;
        float v = tr[c] + pr[c];
        br[c] = f2bf(v);
        sum += v; sq += v*v;
    }
    #pragma unroll
    for (int off=1; off<64; off<<=1){ sum += __shfl_xor(sum,off); sq += __shfl_xor(sq,off); }
    if (lane == 0){
        float* pp = statp + (size_t)row*6;
        pp[0]=sum; pp[1]=sq; pp[2]=0.f; pp[3]=0.f; pp[4]=0.f; pp[5]=0.f;
    }
}

// ---------------- merged transpose-convert (folds LN scale + qscale into weights) ----------------
struct TDesc {
    const float* in; u16* out;
    int Cc; int nx; int perZ; int obDiv; int oStride; int start;
    long inBatch; long oS1; long oS2; float scale;
    const float* svec; long svecS;
};
struct TPack { TDesc d[7]; };

__global__ __launch_bounds__(256) void tconv_all(TPack p){
    __shared__ float tile[32][33];
    int bid = blockIdx.x;
    int e = 0;
    #pragma unroll
    for (int i=1;i<7;++i) e += (bid >= p.d[i].start) ? 1 : 0;
    TDesc D = p.d[e];
    int local = bid - D.start;
    int bz  = local / D.perZ; int rem = local - bz*D.perZ;
    int cy  = rem / D.nx;     int cx  = rem - cy*D.nx;
    int r0 = cy*32, c0 = cx*32;
    const float* ib = D.in + (size_t)bz*D.inBatch;
    u16* ob = D.out + (size_t)(bz/D.obDiv)*D.oS1 + (size_t)(bz%D.obDiv)*D.oS2;
    const float* sv = D.svec ? D.svec + (size_t)(bz/D.obDiv)*D.svecS : nullptr;
    int tx = threadIdx.x & 31, ty = threadIdx.x >> 5;   // 32 x 8
    #pragma unroll
    for (int i=0;i<4;++i) tile[ty+8*i][tx] = ib[(size_t)(r0+ty+8*i)*D.Cc + (c0+tx)];
    __syncthreads();
    float f = D.scale * (sv ? sv[r0+tx] : 1.f);
    #pragma unroll
    for (int i=0;i<4;++i) ob[(size_t)(c0+ty+8*i)*D.oStride + (r0+tx)] = f2bf(tile[tx][ty+8*i]*f);
}

// ---------------- u/v precompute: u[n]=sum_k s[k]W[k,n], v[n]=sum_k b[k]W[k,n] ----------------
struct UVArgs {
    const float *Wq,*Wk,*Wv,*W1,*Wh;
    const float *ln1s,*ln1b,*ln2s,*ln2b,*lnfs,*lnfb;
    float *uvq, *uvf, *uvh; float qscale;
};
__global__ __launch_bounds__(256) void uv_kernel(UVArgs a){
    int gid = blockIdx.x*256 + threadIdx.x;
    const float *W, *s, *b; int kst; float sc = 1.f; float *ou, *ov;
    if (gid < 6*1152){
        int l = gid/1152, n = gid - l*1152;
        int which = n/384, hd = n - which*384, h = hd>>6, d = hd&63;
        const float* Ws = which==0 ? a.Wq : (which==1 ? a.Wk : a.Wv);
        W = Ws + ((size_t)(l*NH+h))*NC*ND + d;
        kst = ND;
        s = a.ln1s + l*NC; b = a.ln1b + l*NC;
        if (which==0) sc = a.qscale;
        ou = a.uvq + (size_t)l*2*1152 + n; ov = ou + 1152;
    } else if (gid < 6*1152 + 6*1536){
        int g = gid - 6*1152; int l = g/1536, f = g - l*1536;
        W = a.W1 + (size_t)l*NC*NFF + f; kst = NFF;
        s = a.ln2s + l*NC; b = a.ln2b + l*NC;
        ou = a.uvf + (size_t)l*2*1536 + f; ov = ou + 1536;
    } else {
        int n = gid - (6*1152 + 6*1536);
        W = a.Wh + n; kst = NV;
        s = a.lnfs; b = a.lnfb;
        ou = a.uvh + n; ov = ou + NV;
    }
    float u = 0.f, v = 0.f;
    for (int k=0;k<NC;++k){ float w = W[(size_t)k*kst]; u += s[k]*w; v += b[k]*w; }
    *ou = u*sc; *ov = v*sc;
}

// ---------------- generic bf16 MFMA GEMM, C = A[M,K] * Bt[N,K]^T ----------------
// r6/r11 structure: BK=64 single-buffer, (256,4). LNF=1: weights are s-folded; epilogue
// applies C = r_m*(G - mu_m*u[n]) + v[n] using stats from statp.
// EPI: 0 = qkv scatter (v transposed), 1 = bf16 residual += C+bias (reads+writes residb),
//      row-stat partials -> stout (BM==32), 2 = relu bf16
template<int EPI, int BM, int BN, int LNF>
__global__ __launch_bounds__(256,4) void gemm_bt(
        const u16* __restrict__ A, const u16* __restrict__ Bt,
        const float* __restrict__ bias, u16* __restrict__ residb,
        u16* __restrict__ outb,
        const float* __restrict__ statp, const float* __restrict__ uvec,
        const float* __restrict__ vvec, float* __restrict__ stout,
        int M, int N, int K){
    constexpr int WM = BM/2, WN = BN/2, MI = WM/16, NI = WN/16;
    __shared__ u16 As[2*BM*32];
    __shared__ u16 Bs[2*BN*32];
    __shared__ float stM[LNF?BM:1], stR[LNF?BM:1];
    __shared__ float sS[2][16][2], sQ[2][16][2];
    int tid = threadIdx.x;
    int lane = tid & 63, wid = tid >> 6;
    int wm = wid >> 1, wn = wid & 1;
    int l15 = lane & 15, lg = lane >> 4;
    int bx = blockIdx.x, by = blockIdx.y;
    int m0 = by * BM, n0 = bx * BN;

    if constexpr (LNF){
        if (tid < BM){
            const float* pp = statp + (size_t)(m0+tid)*6;
            float s = pp[0]+pp[2]+pp[4];
            float q = pp[1]+pp[3]+pp[5];
            float mu = s*(1.f/NC);
            stM[tid] = mu;
            stR[tid] = rsqrtf(q*(1.f/NC) - mu*mu + 1e-5f);
        }
        __syncthreads();
    }

    f32x4 acc[MI][NI];
    #pragma unroll
    for (int a=0;a<MI;++a)
        #pragma unroll
        for (int b=0;b<NI;++b) acc[a][b] = f32x4{0.f,0.f,0.f,0.f};

    int nk = K >> 6;
    for (int kk = 0; kk < nk; ++kk){
        int k0 = kk << 6;
        #pragma unroll
        for (int h=0;h<2;++h){
            if constexpr (BM >= 64){
                #pragma unroll
                for (int i=0;i<BM/64;++i){
                    int o   = i*4096 + tid*16;
                    int row = o >> 6;
                    int kb  = (o & 63) >> 1;
                    gload_lds16(A + (size_t)(m0+row)*K + (k0+h*32+kb), &As[h*BM*32 + (o>>1)]);
                }
            } else {
                if (tid < BM*4){
                    int o = tid*16;
                    int row = o >> 6;
                    int kb  = (o & 63) >> 1;
                    gload_lds16(A + (size_t)(m0+row)*K + (k0+h*32+kb), &As[h*BM*32 + (o>>1)]);
                }
            }
            #pragma unroll
            for (int i=0;i<BN/64;++i){
                int o   = i*4096 + tid*16;
                int row = o >> 6;
                int kb  = (o & 63) >> 1;
                gload_lds16(Bt + (size_t)(n0+row)*K + (k0+h*32+kb), &Bs[h*BN*32 + (o>>1)]);
            }
        }
        asm volatile("s_waitcnt vmcnt(0)" ::: "memory");
        __syncthreads();
        #pragma unroll
        for (int ks=0;ks<2;++ks){
            s16x8 af[MI];
            #pragma unroll
            for (int mi=0;mi<MI;++mi) af[mi] = *(const s16x8*)&As[ks*BM*32 + (wm*WM+mi*16+l15)*32 + lg*8];
            #pragma unroll
            for (int ni=0;ni<NI;++ni){
                s16x8 bfr = *(const s16x8*)&Bs[ks*BN*32 + (wn*WN+ni*16+l15)*32 + lg*8];
                #pragma unroll
                for (int mi=0;mi<MI;++mi)
                    acc[mi][ni] = __builtin_amdgcn_mfma_f32_16x16x32_bf16(af[mi], bfr, acc[mi][ni], 0,0,0);
            }
        }
        __syncthreads();
    }

    if (EPI == 1){
        // bf16 residual += C + bias (read-modify-write residb); per-row stats slot bx
        float rs[4]={0.f,0.f,0.f,0.f}, rq[4]={0.f,0.f,0.f,0.f};
        #pragma unroll
        for (int ni=0;ni<NI;++ni)
            #pragma unroll
            for (int r=0;r<4;++r){
                int mg = m0 + wm*WM + lg*4 + r;
                int ng = n0 + wn*WN + ni*16 + l15;
                u16* pp = residb + (size_t)mg*NC + ng;
                float val = acc[0][ni][r] + bias[ng] + bf2f(*pp);
                *pp = f2bf(val);
                rs[r] += val; rq[r] += val*val;
            }
        #pragma unroll
        for (int r=0;r<4;++r){
            rs[r]+=__shfl_xor(rs[r],1); rq[r]+=__shfl_xor(rq[r],1);
            rs[r]+=__shfl_xor(rs[r],2); rq[r]+=__shfl_xor(rq[r],2);
            rs[r]+=__shfl_xor(rs[r],4); rq[r]+=__shfl_xor(rq[r],4);
            rs[r]+=__shfl_xor(rs[r],8); rq[r]+=__shfl_xor(rq[r],8);
            if (l15==0){ sS[wm][lg*4+r][wn]=rs[r]; sQ[wm][lg*4+r][wn]=rq[r]; }
        }
        __syncthreads();
        if (tid < 32){
            int wmi = tid>>4, rr = tid&15;
            float s = sS[wmi][rr][0] + sS[wmi][rr][1];
            float q = sQ[wmi][rr][0] + sQ[wmi][rr][1];
            float* pp = stout + (size_t)(m0+tid)*6 + bx*2;
            pp[0]=s; pp[1]=q;
        }
        return;
    }

    #pragma unroll
    for (int mi=0;mi<MI;++mi){
        #pragma unroll
        for (int ni=0;ni<NI;++ni){
            int ng = n0 + wn*WN + ni*16 + l15;
            if (EPI == 0){
                int which = ng / NC; int hd = ng - which*NC;
                int hh = hd >> 6, d = hd & 63;
                int mgb = m0 + wm*WM + mi*16 + lg*4;
                int bb = mgb >> 8, tt = mgb & (NT-1);
                float uu = uvec[ng], vv0 = vvec[ng];
                if (which == 2){
                    u16x4 v;
                    #pragma unroll
                    for (int r=0;r<4;++r){
                        int lr = wm*WM + mi*16 + lg*4 + r;
                        v[r] = f2bf(stR[lr]*(acc[mi][ni][r] - stM[lr]*uu) + vv0);
                    }
                    *(u16x4*)(outb + (size_t)2*QKVSZ + ((size_t)(bb*NH+hh)*ND + d)*NT + tt) = v;
                } else {
                    #pragma unroll
                    for (int r=0;r<4;++r){
                        int lr = wm*WM + mi*16 + lg*4 + r;
                        float val = stR[lr]*(acc[mi][ni][r] - stM[lr]*uu) + vv0;
                        outb[(size_t)which*QKVSZ + ((size_t)(bb*NH+hh)*NT + tt+r)*ND + d] = f2bf(val);
                    }
                }
            } else {   // EPI == 2 (FF1 relu)
                float uu = uvec[ng], vv0 = vvec[ng] + bias[ng];
                #pragma unroll
                for (int r=0;r<4;++r){
                    int lr = wm*WM + mi*16 + lg*4 + r;
                    int mg = m0 + lr;
                    float val = stR[lr]*(acc[mi][ni][r] - stM[lr]*uu) + vv0;
                    outb[(size_t)mg*N + ng] = f2bf(fmaxf(val, 0.f));
                }
            }
        }
    }
}

// ---------------- head GEMM: LN-folded logits + loss partials, 2-phase pipelined (r15 config) ----------------
__global__ __launch_bounds__(256,4) void gemm_head(
        const u16* __restrict__ A, const u16* __restrict__ Bt,
        const float* __restrict__ bias,
        const float* __restrict__ statp, const float* __restrict__ uvec,
        const float* __restrict__ vvec,
        float* __restrict__ outf, float* __restrict__ lpart,
        int M, int N, int K){
    constexpr int BM=128, BN=128, WM=64, WN=64, MI=4, NI=4;
    __shared__ u16 As[2][BM*32];
    __shared__ u16 Bs[2][BN*32];
    __shared__ float stM[BM], stR[BM];
    int tid = threadIdx.x;
    int lane = tid & 63, wid = tid >> 6;
    int wm = wid >> 1, wn = wid & 1;
    int l15 = lane & 15, lg = lane >> 4;
    int nwg = gridDim.x*gridDim.y;
    int orig = blockIdx.y*gridDim.x + blockIdx.x;
    int swz = (orig&7)*(nwg>>3) + (orig>>3);
    int by = swz & 31;                        // gridDim.y == 32
    int bx = swz >> 5;
    int m0 = by * BM, n0 = bx * BN;

    if (tid < BM){
        const float* pp = statp + (size_t)(m0+tid)*6;
        float s = pp[0]+pp[2]+pp[4];
        float q = pp[1]+pp[3]+pp[5];
        float mu = s*(1.f/NC);
        stM[tid] = mu;
        stR[tid] = rsqrtf(q*(1.f/NC) - mu*mu + 1e-5f);
    }
    __syncthreads();

    f32x4 acc[MI][NI];
    #pragma unroll
    for (int a=0;a<MI;++a)
        #pragma unroll
        for (int b=0;b<NI;++b) acc[a][b] = f32x4{0.f,0.f,0.f,0.f};

    auto STAGE = [&](int kt, int buf){
        int k0 = kt << 5;
        #pragma unroll
        for (int i=0;i<2;++i){
            int o   = i*4096 + tid*16;
            int row = o >> 6;
            int kb  = (o & 63) >> 1;
            gload_lds16(A + (size_t)(m0+row)*K + (k0+kb), &As[buf][o>>1]);
        }
        #pragma unroll
        for (int i=0;i<2;++i){
            int o   = i*4096 + tid*16;
            int row = o >> 6;
            int kb  = (o & 63) >> 1;
            gload_lds16(Bt + (size_t)(n0+row)*K + (k0+kb), &Bs[buf][o>>1]);
        }
    };

    int nk = K >> 5;                           // 12
    STAGE(0, 0);
    for (int t = 0; t < nk; ++t){
        int buf = t & 1;
        if (t+1 < nk){ STAGE(t+1, buf^1); wait_vm<4>(); }
        else         { wait_vm<0>(); }
        bar();
        s16x8 af[MI];
        #pragma unroll
        for (int mi=0;mi<MI;++mi) af[mi] = *(const s16x8*)&As[buf][(wm*WM+mi*16+l15)*32 + lg*8];
        #pragma unroll
        for (int ni=0;ni<NI;++ni){
            s16x8 bfr = *(const s16x8*)&Bs[buf][(wn*WN+ni*16+l15)*32 + lg*8];
            #pragma unroll
            for (int mi=0;mi<MI;++mi)
                acc[mi][ni] = __builtin_amdgcn_mfma_f32_16x16x32_bf16(af[mi], bfr, acc[mi][ni], 0,0,0);
        }
        bar();
    }

    float es[MI][4];
    #pragma unroll
    for (int mi=0;mi<MI;++mi)
        #pragma unroll
        for (int r=0;r<4;++r) es[mi][r] = 0.f;
    #pragma unroll
    for (int mi=0;mi<MI;++mi)
        #pragma unroll
        for (int ni=0;ni<NI;++ni){
            int ng = n0 + wn*WN + ni*16 + l15;
            float uu = uvec[ng], vv0 = vvec[ng] + bias[ng];
            #pragma unroll
            for (int r=0;r<4;++r){
                int lr = wm*WM + mi*16 + lg*4 + r;
                int mg = m0 + lr;
                float val = stR[lr]*(acc[mi][ni][r] - stM[lr]*uu) + vv0;
                outf[(size_t)mg*N + ng] = val;
                es[mi][r] += __expf(val);
            }
        }
    #pragma unroll
    for (int mi=0;mi<MI;++mi)
        #pragma unroll
        for (int r=0;r<4;++r){
            float s = es[mi][r];
            s += __shfl_xor(s,1); s += __shfl_xor(s,2);
            s += __shfl_xor(s,4); s += __shfl_xor(s,8);
            if (l15 == 0){
                int mg = m0 + wm*WM + mi*16 + lg*4 + r;
                lpart[(size_t)mg*NSLAB + bx*2 + wn] = s;
            }
        }
}

// ---------------- fused causal attention: block per (b,h,qtile64), 4 waves x 16 rows ----------------
__global__ __launch_bounds__(256,2) void attn_kernel(const u16* __restrict__ qkv, u16* __restrict__ o){
    int blk = blockIdx.x;
    int qt = blk & 3, bh = blk >> 2;
    int b = bh / NH, h = bh - b*NH;
    int tid = threadIdx.x, lane = tid & 63, w = tid >> 6;
    int l15 = lane & 15, lg = lane >> 4;
    __shared__ u16 Ks[256*72];
    __shared__ u16 Vt[64*264];
    __shared__ u16 Ps[4][16*72];
    const u16* qb = qkv + (size_t)bh*NT*ND;
    const u16* kb = qkv + QKVSZ + (size_t)bh*NT*ND;
    const u16* vb = qkv + (size_t)2*QKVSZ + (size_t)bh*ND*NT;   // transposed [d][t]
    int nit = (qt+1)*2;
    for (int it=0; it<nit; ++it){
        int e0 = (it*256 + tid)*8;
        int row = e0 >> 6, col = e0 & 63;
        *(u16x8*)&Ks[row*72+col] = *(const u16x8*)(kb + e0);
    }
    for (int kt2=0; kt2<=qt; ++kt2){
        #pragma unroll
        for (int it=0; it<2; ++it){
            int e0 = (it*256 + tid)*8;
            int d = e0 >> 6, t = e0 & 63;
            *(u16x8*)&Vt[d*264 + kt2*64 + t] = *(const u16x8*)(vb + (size_t)d*NT + kt2*64 + t);
        }
    }
    const u16* qrow = qb + (size_t)(qt*64 + w*16 + l15)*ND;
    s16x8 qf[2];
    qf[0] = *(const s16x8*)(qrow + lg*8);
    qf[1] = *(const s16x8*)(qrow + 32 + lg*8);
    __syncthreads();

    f32x4 oacc[4]; float l_[4];
    #pragma unroll
    for (int c=0;c<4;++c){ oacc[c]=f32x4{0.f,0.f,0.f,0.f}; l_[c]=0.f; }
    u16* Pw = &Ps[w][0];

    for (int kt=0; kt<=qt; ++kt){
        f32x4 sacc[4];
        #pragma unroll
        for (int c=0;c<4;++c) sacc[c]=f32x4{0.f,0.f,0.f,0.f};
        #pragma unroll
        for (int ks=0;ks<2;++ks){
            s16x8 kf[4];
            #pragma unroll
            for (int ni=0;ni<4;++ni)
                kf[ni] = *(const s16x8*)&Ks[(kt*64+ni*16+l15)*72 + ks*32 + lg*8];
            #pragma unroll
            for (int ni=0;ni<4;++ni)
                sacc[ni] = __builtin_amdgcn_mfma_f32_16x16x32_bf16(qf[ks], kf[ni], sacc[ni], 0,0,0);
        }
        if (kt == qt){
            #pragma unroll
            for (int ni=0;ni<4;++ni)
                #pragma unroll
                for (int r=0;r<4;++r)
                    if (ni*16+l15 > w*16+lg*4+r) sacc[ni][r] = -1e30f;
        }
        #pragma unroll
        for (int r=0;r<4;++r){
            float rs = 0.f;
            #pragma unroll
            for (int ni=0;ni<4;++ni){
                float p = __expf(sacc[ni][r]);
                sacc[ni][r] = p;
                rs += p;
                Pw[(lg*4+r)*72 + ni*16 + l15] = f2bf(p);
            }
            rs += __shfl_xor(rs,1); rs += __shfl_xor(rs,2);
            rs += __shfl_xor(rs,4); rs += __shfl_xor(rs,8);
            l_[r] += rs;
        }
        #pragma unroll
        for (int ks=0;ks<2;++ks){
            s16x8 pf, vf[4];
            pf = *(const s16x8*)&Pw[l15*72 + ks*32 + lg*8];
            #pragma unroll
            for (int ni=0;ni<4;++ni)
                vf[ni] = *(const s16x8*)&Vt[(ni*16+l15)*264 + kt*64 + ks*32 + lg*8];
            #pragma unroll
            for (int ni=0;ni<4;++ni)
                oacc[ni] = __builtin_amdgcn_mfma_f32_16x16x32_bf16(pf, vf[ni], oacc[ni], 0,0,0);
        }
    }
    #pragma unroll
    for (int ni=0;ni<4;++ni)
        #pragma unroll
        for (int r=0;r<4;++r){
            int t = qt*64 + w*16 + lg*4 + r;
            int d = ni*16 + l15;
            o[((size_t)(b*NT + t))*NC + h*ND + d] = f2bf(oacc[ni][r] / l_[r]);
        }
}

// ---------------- loss: reduce per-row slab partials ----------------
__global__ __launch_bounds__(256) void loss_rows2(const float* __restrict__ lpart,
        const float* __restrict__ logits, const int* __restrict__ y, float* __restrict__ rowloss){
    int row  = blockIdx.x*4 + (threadIdx.x>>6);
    int lane = threadIdx.x & 63;
    const float* pr = lpart + (size_t)row*NSLAB;
    float s = 0.f;
    for (int i = lane; i < NSLAB; i += 64) s += pr[i];
    #pragma unroll
    for (int off=1; off<64; off<<=1) s += __shfl_xor(s, off);
    if (lane==0)
        rowloss[row] = logf(s) - logits[(size_t)row*NV + y[row]];
}

__global__ __launch_bounds__(256) void loss_final(const float* __restrict__ rowloss, float* __restrict__ out){
    int tid = threadIdx.x;
    float s = 0.f;
    for (int i = tid; i < NM; i += 256) s += rowloss[i];
    #pragma unroll
    for (int off=1; off<64; off<<=1) s += __shfl_xor(s, off);
    __shared__ float ss[4];
    if ((tid&63)==0) ss[tid>>6]=s;
    __syncthreads();
    if (tid==0) out[0] = (ss[0]+ss[1]+ss[2]+ss[3]) * (1.f/NM);
}

// ---------------- launch ----------------
extern "C" void kernel_launch(void* const* d_in, const int* in_sizes, int n_in,
                              void* d_out, int out_size, void* d_ws, size_t ws_size,
                              hipStream_t stream){
    const int*   x_ids = (const int*)  d_in[0];
    const int*   y_ids = (const int*)  d_in[1];
    const float* tok   = (const float*)d_in[2];
    const float* pos   = (const float*)d_in[3];
    const float* Wq    = (const float*)d_in[4];
    const float* Wk    = (const float*)d_in[5];
    const float* Wv    = (const float*)d_in[6];
    const float* Wo    = (const float*)d_in[7];
    const float* bo    = (const float*)d_in[8];
    const float* ln1s  = (const float*)d_in[9];
    const float* ln1b  = (const float*)d_in[10];
    const float* ln2s  = (const float*)d_in[11];
    const float* ln2b  = (const float*)d_in[12];
    const float* W1    = (const float*)d_in[13];
    const float* b1    = (const float*)d_in[14];
    const float* W2    = (const float*)d_in[15];
    const float* b2    = (const float*)d_in[16];
    const float* lnfs  = (const float*)d_in[17];
    const float* lnfb  = (const float*)d_in[18];
    const float* Wh    = (const float*)d_in[19];
    const float* bh    = (const float*)d_in[20];

    float* logits = (float*)d_out;
    float* lossp  = logits + (size_t)NM*NV;

    char* ws = (char*)d_ws;
    auto alloc = [&](size_t bytes)->char*{ char* p = ws; ws += (bytes + 255) & ~(size_t)255; return p; };
    u16*   xb    = (u16*)  alloc((size_t)NM*NC*2);      // bf16 residual stream
    float* statp = (float*)alloc((size_t)NM*6*4);
    u16*   qkvb  = (u16*)  alloc((size_t)3*QKVSZ*2);    // reused as fp32 loss partials
    u16*   obf   = (u16*)  alloc((size_t)NM*NC*2);
    u16*   f1bf  = (u16*)  alloc((size_t)NM*NFF*2);
    u16*   qkvw  = (u16*)  alloc((size_t)NL*1152*NC*2);
    u16*   wot   = (u16*)  alloc((size_t)NL*NC*NC*2);
    u16*   w1t   = (u16*)  alloc((size_t)NL*NFF*NC*2);
    u16*   w2t   = (u16*)  alloc((size_t)NL*NC*NFF*2);
    u16*   wht   = (u16*)  alloc((size_t)NV*NC*2);
    float* uvq   = (float*)alloc((size_t)NL*2*1152*4);
    float* uvf   = (float*)alloc((size_t)NL*2*1536*4);
    float* uvh   = (float*)alloc((size_t)2*NV*4);
    float* part  = (float*)alloc((size_t)NM*4);
    float* lpart = (float*)qkvb;

    const float qscale = 0.051031036307982884f;   // 384^-0.5

    // ---- weight conversion (LN scale + qscale folded) ----
    TPack tp;
    tp.d[0] = {Wq, qkvw + 0*(NC*NC), ND,  2,  24, NH, NC, 0,     (long)NC*ND, (long)1152*NC, (long)ND*NC, qscale, ln1s, NC};
    tp.d[1] = {Wk, qkvw + 1*(NC*NC), ND,  2,  24, NH, NC, 864,   (long)NC*ND, (long)1152*NC, (long)ND*NC, 1.f,    ln1s, NC};
    tp.d[2] = {Wv, qkvw + 2*(NC*NC), ND,  2,  24, NH, NC, 1728,  (long)NC*ND, (long)1152*NC, (long)ND*NC, 1.f,    ln1s, NC};
    tp.d[3] = {Wo, wot,              NC, 12, 144, 1,  NC, 2592,  (long)NC*NC, (long)NC*NC,   0,           1.f,    nullptr, 0};
    tp.d[4] = {W1, w1t,             NFF, 48, 576, 1,  NC, 3456,  (long)NC*NFF,(long)NFF*NC,  0,           1.f,    ln2s, NC};
    tp.d[5] = {W2, w2t,              NC, 12, 576, 1, NFF, 6912,  (long)NFF*NC,(long)NC*NFF,  0,           1.f,    nullptr, 0};
    tp.d[6] = {Wh, wht,              NV,1000,12000,1, NC, 10368, 0,           0,             0,           1.f,    lnfs, 0};
    tconv_all<<<22368,256,0,stream>>>(tp);

    UVArgs ua = {Wq, Wk, Wv, W1, Wh, ln1s, ln1b, ln2s, ln2b, lnfs, lnfb, uvq, uvf, uvh, qscale};
    uv_kernel<<<(6*1152 + 6*1536 + NV)/256, 256, 0, stream>>>(ua);

    // ---- forward ----
    embed_stats<<<NM/4,256,0,stream>>>(x_ids, tok, pos, xb, statp);
    for (int l = 0; l < NL; ++l){
        gemm_bt<0,64,128,1><<<dim3(1152/128, NM/64),256,0,stream>>>(
                xb, qkvw + (size_t)l*1152*NC, nullptr, nullptr, qkvb,
                statp, uvq + (size_t)l*2*1152, uvq + (size_t)l*2*1152 + 1152, nullptr,
                NM, 1152, NC);
        attn_kernel<<<NB*NH*4,256,0,stream>>>(qkvb, obf);
        gemm_bt<1,32,128,0><<<dim3(NC/128, NM/32),256,0,stream>>>(
                obf, wot + (size_t)l*NC*NC, bo + l*NC, xb, nullptr,
                nullptr, nullptr, nullptr, statp, NM, NC, NC);
        gemm_bt<2,64,128,1><<<dim3(NFF/128, NM/64),256,0,stream>>>(
                xb, w1t + (size_t)l*NFF*NC, b1 + l*NFF, nullptr, f1bf,
                statp, uvf + (size_t)l*2*1536, uvf + (size_t)l*2*1536 + 1536, nullptr,
                NM, NFF, NC);
        gemm_bt<1,32,128,0><<<dim3(NC/128, NM/32),256,0,stream>>>(
                f1bf, w2t + (size_t)l*NC*NFF, b2 + l*NC, xb, nullptr,
                nullptr, nullptr, nullptr, statp, NM, NC, NFF);
    }
    gemm_head<<<dim3(NV/128, NM/128),256,0,stream>>>(xb, wht, bh,
            statp, uvh, uvh + NV, logits, lpart, NM, NV, NC);
    loss_rows2<<<NM/4,256,0,stream>>>(lpart, logits, y_ids, part);
    loss_final<<<1,256,0,stream>>>(part, lossp);
}